// Round 1
// baseline (23.593 us; speedup 1.0000x reference)
//
#include <hip/hip_runtime.h>

// Routed embedding-bag sum-pool.
//   inputs: feature_ids[N] (unused: routing already baked into query_results),
//           offsets[B], query_results[N], hot_W[(HOT+1)*D], hash_W[HASH*D]
//   output: out[B*D] fp32, D=128
//
// One block per bag. 128 threads; thread d owns output dim d.
// Stage per-token row pointers in LDS, then sweep tokens with coalesced
// 512B row reads, accumulating in a register.

#define TOK_CHUNK 128
#define EMB_D 128

__global__ __launch_bounds__(EMB_D)
void embbag_kernel(const int* __restrict__ qr,
                   const int* __restrict__ offsets,
                   const float* __restrict__ hot_W,
                   const float* __restrict__ hash_W,
                   float* __restrict__ out,
                   int N, int B, int hot_rows, int hash_rows) {
    const int b = blockIdx.x;
    const int d = threadIdx.x;  // 0..127
    const int start = offsets[b];
    const int end = (b + 1 < B) ? offsets[b + 1] : N;

    __shared__ const float* rows[TOK_CHUNK];

    float acc = 0.0f;
    for (int base = start; base < end; base += TOK_CHUNK) {
        const int cnt = min(TOK_CHUNK, end - base);
        if (d < cnt) {
            const int q = qr[base + d];
            const float* r;
            if (q < 0) {
                int hi = -q;                       // 1 .. HOT
                const int mx = hot_rows - 1;       // clip to table
                if (hi > mx) hi = mx;
                r = hot_W + (size_t)hi * EMB_D;
            } else {
                r = hash_W + (size_t)(q % hash_rows) * EMB_D;
            }
            rows[d] = r;
        }
        __syncthreads();
        #pragma unroll 4
        for (int t = 0; t < cnt; ++t) {
            acc += rows[t][d];
        }
        __syncthreads();
    }
    out[(size_t)b * EMB_D + d] = acc;
}

extern "C" void kernel_launch(void* const* d_in, const int* in_sizes, int n_in,
                              void* d_out, int out_size, void* d_ws, size_t ws_size,
                              hipStream_t stream) {
    // setup_inputs order: feature_ids, offsets, query_results, hot_W, hash_W
    const int*   offsets = (const int*)d_in[1];
    const int*   qr      = (const int*)d_in[2];
    const float* hot_W   = (const float*)d_in[3];
    const float* hash_W  = (const float*)d_in[4];
    float*       out     = (float*)d_out;

    const int N         = in_sizes[0];
    const int B         = in_sizes[1];
    const int hot_rows  = in_sizes[3] / EMB_D;
    const int hash_rows = in_sizes[4] / EMB_D;

    embbag_kernel<<<B, EMB_D, 0, stream>>>(qr, offsets, hot_W, hash_W, out,
                                           N, B, hot_rows, hash_rows);
}

// Round 2
// 22.764 us; speedup vs baseline: 1.0364x; 1.0364x over previous
//
#include <hip/hip_runtime.h>

// Routed embedding-bag sum-pool.
//   inputs: feature_ids[N] (unused), offsets[B], query_results[N],
//           hot_W[(HOT+1)*D], hash_W[HASH*D]    (fp32, D=128)
//   output: out[B*D] fp32
//
// One block (128 threads) per bag.
//   Phase 1: resolve up to 128 token row pointers into LDS.
//   Phase 2: 4 half-wave groups (32 lanes each) sweep tokens 4-at-a-time;
//            each lane reads float4 (16B) -> one row = 32 lanes * 16B = 512B
//            per load instruction, fully coalesced.
//   Phase 3: one-time LDS reduction across the 4 groups (conflict-free).

#define TOK_CHUNK 128
#define EMB_D 128

__global__ __launch_bounds__(EMB_D)
void embbag_kernel(const int* __restrict__ qr,
                   const int* __restrict__ offsets,
                   const float* __restrict__ hot_W,
                   const float* __restrict__ hash_W,
                   float* __restrict__ out,
                   int N, int B, int hot_rows, int hash_rows) {
    const int b   = blockIdx.x;
    const int tid = threadIdx.x;   // 0..127
    const int g   = tid >> 5;      // token group 0..3
    const int c   = tid & 31;      // dim-quad index 0..31
    const int start = offsets[b];
    const int end   = (b + 1 < B) ? offsets[b + 1] : N;

    __shared__ const float* rows[TOK_CHUNK];
    __shared__ float red[4][EMB_D];

    float4 acc = {0.0f, 0.0f, 0.0f, 0.0f};
    for (int base = start; base < end; base += TOK_CHUNK) {
        const int cnt = min(TOK_CHUNK, end - base);
        if (tid < cnt) {
            const int q = qr[base + tid];
            const float* r;
            if (q < 0) {
                int hi = -q;                     // 1 .. HOT
                const int mx = hot_rows - 1;     // clip
                if (hi > mx) hi = mx;
                r = hot_W + (size_t)hi * EMB_D;
            } else {
                r = hash_W + (size_t)(q % hash_rows) * EMB_D;
            }
            rows[tid] = r;
        }
        __syncthreads();
        #pragma unroll 4
        for (int t = g; t < cnt; t += 4) {
            const float4 v = *(const float4*)(rows[t] + c * 4);
            acc.x += v.x; acc.y += v.y; acc.z += v.z; acc.w += v.w;
        }
        __syncthreads();
    }

    // reduce the 4 token-groups' partials
    *(float4*)&red[g][c * 4] = acc;
    __syncthreads();
    const float s = red[0][tid] + red[1][tid] + red[2][tid] + red[3][tid];
    out[(size_t)b * EMB_D + tid] = s;
}

extern "C" void kernel_launch(void* const* d_in, const int* in_sizes, int n_in,
                              void* d_out, int out_size, void* d_ws, size_t ws_size,
                              hipStream_t stream) {
    // setup_inputs order: feature_ids, offsets, query_results, hot_W, hash_W
    const int*   offsets = (const int*)d_in[1];
    const int*   qr      = (const int*)d_in[2];
    const float* hot_W   = (const float*)d_in[3];
    const float* hash_W  = (const float*)d_in[4];
    float*       out     = (float*)d_out;

    const int N         = in_sizes[0];
    const int B         = in_sizes[1];
    const int hot_rows  = in_sizes[3] / EMB_D;
    const int hash_rows = in_sizes[4] / EMB_D;

    embbag_kernel<<<B, EMB_D, 0, stream>>>(qr, offsets, hot_W, hash_W, out,
                                           N, B, hot_rows, hash_rows);
}